// Round 1
// baseline (120.468 us; speedup 1.0000x reference)
//
#include <hip/hip_runtime.h>

#define IMH 512
#define IMW 512
#define NB 32
#define NPIX (NB*IMH*IMW)            // 8388608
#define WPI  (IMH*(IMW/64))          // 4096 words per image
#define NWORDS (NB*WPI)              // 131072
#define T_PASSES 24

typedef unsigned long long u64;

// ------------------------------------------------------------------
// Kernel 1: quantize + Sobel + NMS -> bitpacked strong/weak masks
// block (64,8): each wave = one 64-px row segment -> one 64-bit word
// ------------------------------------------------------------------
__global__ __launch_bounds__(512) void k_sobel_nms(
    const float* __restrict__ labels,
    u64* __restrict__ edgew,   // initialized to strong
    u64* __restrict__ weakw)
{
    __shared__ float simg[12][68];   // img tile + 2-halo
    __shared__ float smag[10][66];   // mag tile + 1-halo

    const int xw = blockIdx.x;       // 0..7 (word column)
    const int yt = blockIdx.y;       // 0..63 (8-row tiles)
    const int b  = blockIdx.z;       // image
    const int x0 = xw*64, y0 = yt*8;
    const int tx = threadIdx.x, ty = threadIdx.y;
    const int tid = ty*64 + tx;
    const float* img = labels + (size_t)b*IMH*IMW;

    // load quantized image tile (replicate border)
    for (int i = tid; i < 12*68; i += 512) {
        int r = i/68, c = i - r*68;
        int gy = min(max(y0-2+r, 0), IMH-1);
        int gx = min(max(x0-2+c, 0), IMW-1);
        float v = img[gy*IMW + gx];
        v = fminf(fmaxf(v, 0.f), 1.f);
        simg[r][c] = floorf(v*255.f);
    }
    __syncthreads();

    // mag tile (+1 halo); zero outside image (NMS shifts are zero-padded)
    for (int i = tid; i < 10*66; i += 512) {
        int r = i/66, c = i - r*66;
        int gy = y0-1+r, gx = x0-1+c;
        float m = 0.f;
        if (gy >= 0 && gy < IMH && gx >= 0 && gx < IMW) {
            float a00=simg[r][c],   a01=simg[r][c+1],   a02=simg[r][c+2];
            float a10=simg[r+1][c],                     a12=simg[r+1][c+2];
            float a20=simg[r+2][c], a21=simg[r+2][c+1], a22=simg[r+2][c+2];
            float gxv = (a02 + 2.f*a12 + a22) - (a00 + 2.f*a10 + a20);
            float gyv = (a20 + 2.f*a21 + a22) - (a00 + 2.f*a01 + a02);
            m = fabsf(gxv) + fabsf(gyv);
        }
        smag[r][c] = m;
    }
    __syncthreads();

    // NMS at center pixel
    const int r = ty+2, c = tx+2;
    float a00=simg[r-1][c-1], a01=simg[r-1][c], a02=simg[r-1][c+1];
    float a10=simg[r][c-1],                     a12=simg[r][c+1];
    float a20=simg[r+1][c-1], a21=simg[r+1][c], a22=simg[r+1][c+1];
    float gxv = (a02 + 2.f*a12 + a22) - (a00 + 2.f*a10 + a20);
    float gyv = (a20 + 2.f*a21 + a22) - (a00 + 2.f*a01 + a02);
    float m = smag[ty+1][tx+1];

    float ax = fabsf(gxv), ay = fabsf(gyv);
    const float T1 = 0.41421356237309503f;   // tan 22.5
    const float T2 = 2.4142135623730951f;    // tan 67.5
    bool bb0  = ay <  T1*ax;
    bool bb90 = ay >= T2*ax;
    bool bb45 = (!bb0) && (!bb90) && (gxv*gyv > 0.f);

    int dy1, dx1, dy2, dx2;
    if (bb0)       { dy1=0;  dx1=1;  dy2=0;  dx2=-1; }
    else if (bb45) { dy1=-1; dx1=1;  dy2=1;  dx2=-1; }
    else if (bb90) { dy1=1;  dx1=0;  dy2=-1; dx2=0;  }
    else           { dy1=-1; dx1=-1; dy2=1;  dx2=1;  }

    float n1 = smag[ty+1+dy1][tx+1+dx1];
    float n2 = smag[ty+1+dy2][tx+1+dx2];
    bool nms = (m >= n1) && (m >= n2);
    bool strongp = nms && (m > 200.f);
    bool weakp   = nms && (m > 100.f);

    u64 wm = __ballot(weakp);
    u64 sm = __ballot(strongp);
    if (tx == 0) {
        int idx = (b*IMH + (y0+ty))*8 + xw;
        weakw[idx] = wm;
        edgew[idx] = sm;
    }
}

// ------------------------------------------------------------------
// Kernel 2: one in-place dilate-and-mask pass over bitpacked words.
// Monotone lattice -> in-place races are safe. Early-exit flag chain.
// ------------------------------------------------------------------
__device__ inline u64 hz(u64 l, u64 cc, u64 rr) {
    return cc | (cc<<1) | (cc>>1) | (l>>63) | (rr<<63);
}

__global__ __launch_bounds__(256) void k_hyst(
    u64* __restrict__ edgew,
    const u64* __restrict__ weakw,
    int* __restrict__ flags, int p)
{
    if (p > 0 && flags[p-1] == 0) return;
    int w = blockIdx.x*256 + threadIdx.x;
    if (w >= NWORDS) return;
    int b   = w >> 12;
    int rem = w & 4095;
    int y   = rem >> 3, xw = rem & 7;
    const u64* eb = edgew + b*WPI;

    u64 l0=0,c0=0,r0=0, lm=0,cm=0,rm=0, lp=0,cp=0,rp=0;
    {
        int ro = y*8;
        if (xw > 0) l0 = eb[ro+xw-1];
        c0 = eb[ro+xw];
        if (xw < 7) r0 = eb[ro+xw+1];
    }
    if (y > 0) {
        int ro = (y-1)*8;
        if (xw > 0) lm = eb[ro+xw-1];
        cm = eb[ro+xw];
        if (xw < 7) rm = eb[ro+xw+1];
    }
    if (y < IMH-1) {
        int ro = (y+1)*8;
        if (xw > 0) lp = eb[ro+xw-1];
        cp = eb[ro+xw];
        if (xw < 7) rp = eb[ro+xw+1];
    }
    u64 dil = hz(lm,cm,rm) | hz(l0,c0,r0) | hz(lp,cp,rp);
    u64 nw  = weakw[w] & dil;
    if (nw != c0) {
        edgew[w] = nw;
        flags[p] = 1;   // benign race, all write 1
    }
}

// ------------------------------------------------------------------
// Kernel 3: NLL loss sum (double accumulation)
// ------------------------------------------------------------------
__global__ __launch_bounds__(256) void k_loss(
    const float* __restrict__ pred,
    const u64* __restrict__ edgew,
    double* __restrict__ acc)
{
    double s = 0.0;
    int stride = gridDim.x*256;
    for (int i = blockIdx.x*256 + threadIdx.x; i < NPIX; i += stride) {
        int b   = i >> 18;
        int rem = i & 262143;
        u64 wrd = edgew[(b<<12) | (rem>>6)];
        int cbit = (int)((wrd >> (rem & 63)) & 1ull);
        float p0 = pred[(size_t)(b*2)*262144 + rem];
        float p1 = pred[(size_t)(b*2+1)*262144 + rem];
        float mx = fmaxf(p0, p1);
        float lse = mx + logf(expf(p0-mx) + expf(p1-mx));
        float chosen = cbit ? p1 : p0;
        s += (double)(lse - chosen);
    }
    // wave reduce
    for (int off = 32; off > 0; off >>= 1) s += __shfl_down(s, off);
    __shared__ double ssum[4];
    int lane = threadIdx.x & 63, wv = threadIdx.x >> 6;
    if (lane == 0) ssum[wv] = s;
    __syncthreads();
    if (threadIdx.x == 0) {
        double t = ssum[0] + ssum[1] + ssum[2] + ssum[3];
        atomicAdd(acc, t);
    }
}

__global__ void k_final(const double* __restrict__ acc, float* __restrict__ out) {
    out[0] = (float)(acc[0] * (1.0/8388608.0));
}

// ------------------------------------------------------------------
extern "C" void kernel_launch(void* const* d_in, const int* in_sizes, int n_in,
                              void* d_out, int out_size, void* d_ws, size_t ws_size,
                              hipStream_t stream)
{
    const float* pred   = (const float*)d_in[0];
    const float* labels = (const float*)d_in[1];
    float* out = (float*)d_out;

    char* ws = (char*)d_ws;
    double* acc   = (double*)ws;                    // 8 B
    int*    flags = (int*)(ws + 8);                 // T_PASSES ints
    u64*    edgew = (u64*)(ws + 4096);              // 1 MB
    u64*    weakw = edgew + NWORDS;                 // 1 MB

    hipMemsetAsync(ws, 0, 4096, stream);            // zero acc + flags

    dim3 blk(64, 8);
    dim3 grd(8, 64, 32);
    k_sobel_nms<<<grd, blk, 0, stream>>>(labels, edgew, weakw);

    for (int p = 0; p < T_PASSES; ++p)
        k_hyst<<<512, 256, 0, stream>>>(edgew, weakw, flags, p);

    k_loss<<<2048, 256, 0, stream>>>(pred, edgew, acc);
    k_final<<<1, 1, 0, stream>>>(acc, out);
}